// Round 1
// baseline (447.014 us; speedup 1.0000x reference)
//
#include <hip/hip_runtime.h>

typedef __attribute__((ext_vector_type(8))) _Float16 f16x8;
typedef __attribute__((ext_vector_type(4))) float f32x4;

#define EPSV 1e-5f
#define BB 8
#define CC 256
#define NP 4096
#define FF 128

static __device__ __forceinline__ unsigned short f2h(float f) {
    union { _Float16 h; unsigned short u; } v;
    v.h = (_Float16)f;
    return v.u;
}

// ---------------------------------------------------------------- prep
struct PrepArgs {
    const float* w[3]; const float* bias[3]; const float* g[3]; const float* be[3];
    const float* m[3]; const float* v[3];
    const float* pre_w; const float* pre_b;
    const float* post_g; const float* post_be; const float* post_m; const float* post_v;
    unsigned short* W_all; float* b_all; unsigned short* W2; float* b2; float* sres;
};

__global__ __launch_bounds__(256) void prep_kernel(PrepArgs a) {
    int idx = blockIdx.x * 256 + threadIdx.x;
    if (idx < 3 * 128 * 256) {
        int row = idx >> 8, c = idx & 255;
        int which = row >> 7, f = row & 127;
        float s = a.g[which][f] * rsqrtf(a.v[which][f] + EPSV);
        a.W_all[idx] = f2h(a.w[which][f * 256 + c] * s);
        if (c == 0)
            a.b_all[row] = s * a.bias[which][f] + a.be[which][f] - a.m[which][f] * s;
    } else {
        int i = idx - 3 * 128 * 256;
        if (i < 256 * 128) {
            int c = i >> 7, f = i & 127;
            float s = a.post_g[c] * rsqrtf(a.post_v[c] + EPSV);
            a.W2[i] = f2h(a.pre_w[i] * s);
            if (f == 0) {
                a.b2[c] = s * a.pre_b[c] + a.post_be[c] - a.post_m[c] * s;
                a.sres[c] = s;
            }
        }
    }
}

// ---------------------------------------------------------------- transpose x -> xT f16
__global__ __launch_bounds__(256) void transpose_x_kernel(const float* __restrict__ x,
                                                          unsigned short* __restrict__ xT) {
    __shared__ float tile[64][65];
    int blk = blockIdx.x;           // 8 * 4 * 64
    int b  = blk >> 8;
    int c0 = ((blk >> 6) & 3) << 6;
    int n0 = (blk & 63) << 6;
    int t = threadIdx.x;
    const float* src = x + ((size_t)b * CC + c0) * NP + n0;
    #pragma unroll
    for (int i = 0; i < 16; ++i) {
        int cl = i * 4 + (t >> 6);
        tile[cl][t & 63] = src[(size_t)cl * NP + (t & 63)];
    }
    __syncthreads();
    unsigned short* dst = xT + ((size_t)b * NP + n0) * CC + c0;
    #pragma unroll
    for (int i = 0; i < 8; ++i) {
        int nl = i * 8 + (t >> 5);
        int cl = (t & 31) * 2;
        unsigned lo = f2h(tile[cl][nl]);
        unsigned hi = f2h(tile[cl + 1][nl]);
        *reinterpret_cast<unsigned*>(dst + (size_t)nl * CC + cl) = (hi << 16) | lo;
    }
}

// ---------------------------------------------------------------- qkv gemm
// Out_T[n][f] = relu(sum_c xT[n][c] * W_all[fbase+f][c] + b_all[fbase+f])
// ft 0 -> tq [N][F], ft 1 -> kp [N][F], ft 2 -> vz [F][N] (transposed store)
__global__ __launch_bounds__(256) void qkv_kernel(const unsigned short* __restrict__ xT,
                                                  const unsigned short* __restrict__ W_all,
                                                  const float* __restrict__ b_all,
                                                  unsigned short* __restrict__ tq,
                                                  unsigned short* __restrict__ kp,
                                                  unsigned short* __restrict__ vz) {
    __shared__ unsigned short Alds[128 * 72];
    __shared__ unsigned short Blds[128 * 72];
    int blk = blockIdx.x;           // 768 = 8 batches * 3 ftiles * 32 ntiles
    int b  = blk & 7;               // XCD-affine batch
    int r  = blk >> 3;              // 0..95
    int ft = r >> 5;                // 0..2
    int n0 = (r & 31) << 7;
    int fbase = ft << 7;
    int t = threadIdx.x, w = t >> 6, l = t & 63;
    int wr = (w >> 1) << 6, wc = (w & 1) << 6;
    const unsigned short* A  = xT + ((size_t)b * NP + n0) * CC;
    const unsigned short* Bw = W_all + (size_t)fbase * CC;

    f32x4 acc[4][4];
    #pragma unroll
    for (int i = 0; i < 4; ++i)
        #pragma unroll
        for (int j = 0; j < 4; ++j)
            acc[i][j] = f32x4{0.f, 0.f, 0.f, 0.f};

    for (int c0 = 0; c0 < 256; c0 += 64) {
        #pragma unroll
        for (int i = 0; i < 4; ++i) {
            int row = i * 32 + (t >> 3);
            int ch = (t & 7) * 8;
            *reinterpret_cast<int4*>(&Alds[row * 72 + ch]) =
                *reinterpret_cast<const int4*>(A + (size_t)row * CC + c0 + ch);
            *reinterpret_cast<int4*>(&Blds[row * 72 + ch]) =
                *reinterpret_cast<const int4*>(Bw + (size_t)row * CC + c0 + ch);
        }
        __syncthreads();
        #pragma unroll
        for (int kk = 0; kk < 2; ++kk) {
            f16x8 af[4], bfr[4];
            #pragma unroll
            for (int mi = 0; mi < 4; ++mi)
                af[mi] = *reinterpret_cast<const f16x8*>(
                    &Alds[(wr + mi * 16 + (l & 15)) * 72 + kk * 32 + (l >> 4) * 8]);
            #pragma unroll
            for (int ni = 0; ni < 4; ++ni)
                bfr[ni] = *reinterpret_cast<const f16x8*>(
                    &Blds[(wc + ni * 16 + (l & 15)) * 72 + kk * 32 + (l >> 4) * 8]);
            #pragma unroll
            for (int mi = 0; mi < 4; ++mi)
                #pragma unroll
                for (int ni = 0; ni < 4; ++ni)
                    acc[mi][ni] = __builtin_amdgcn_mfma_f32_16x16x32_f16(af[mi], bfr[ni], acc[mi][ni], 0, 0, 0);
        }
        __syncthreads();
    }

    #pragma unroll
    for (int mi = 0; mi < 4; ++mi) {
        #pragma unroll
        for (int ni = 0; ni < 4; ++ni) {
            int fl = wc + ni * 16 + (l & 15);
            float bias = b_all[fbase + fl];
            int nb = n0 + wr + mi * 16 + ((l >> 4) << 2);
            if (ft == 2) {
                unsigned pk0, pk1;
                float v0 = acc[mi][ni][0] + bias; v0 = v0 > 0.f ? v0 : 0.f;
                float v1 = acc[mi][ni][1] + bias; v1 = v1 > 0.f ? v1 : 0.f;
                float v2 = acc[mi][ni][2] + bias; v2 = v2 > 0.f ? v2 : 0.f;
                float v3 = acc[mi][ni][3] + bias; v3 = v3 > 0.f ? v3 : 0.f;
                pk0 = (unsigned)f2h(v0) | ((unsigned)f2h(v1) << 16);
                pk1 = (unsigned)f2h(v2) | ((unsigned)f2h(v3) << 16);
                uint2 uu; uu.x = pk0; uu.y = pk1;
                *reinterpret_cast<uint2*>(vz + (size_t)b * FF * NP + (size_t)fl * NP + nb) = uu;
            } else {
                unsigned short* dst = (ft == 0 ? tq : kp) + (size_t)b * NP * FF;
                #pragma unroll
                for (int rg = 0; rg < 4; ++rg) {
                    float v = acc[mi][ni][rg] + bias;
                    dst[(size_t)(nb + rg) * FF + fl] = f2h(v > 0.f ? v : 0.f);
                }
            }
        }
    }
}

// ---------------------------------------------------------------- flash attention
// u[n][f] = sum_m softmax_m(sum_f' t[n][f'] p[m][f']) * z[f][m]
__global__ __launch_bounds__(256) void attn_kernel(const unsigned short* __restrict__ tq,
                                                   const unsigned short* __restrict__ kp,
                                                   const unsigned short* __restrict__ vz,
                                                   unsigned short* __restrict__ uT) {
    __shared__ unsigned short Klds[32 * 136];
    __shared__ unsigned short Vlds[128 * 40];
    __shared__ unsigned short Plds[4][32 * 40];
    int blk = blockIdx.x;           // 256 = 8 batches * 32 qtiles
    int b  = blk & 7;               // XCD-affine batch -> K/V stays in one XCD L2
    int qt = blk >> 3;
    int t = threadIdx.x, w = t >> 6, l = t & 63;
    int n0 = qt * 128 + w * 32;     // this wave's 32 Q rows
    const unsigned short* Q = tq + (size_t)b * NP * FF;
    const unsigned short* K = kp + (size_t)b * NP * FF;
    const unsigned short* V = vz + (size_t)b * FF * NP;

    f16x8 qa[2][4];
    #pragma unroll
    for (int g = 0; g < 2; ++g)
        #pragma unroll
        for (int k = 0; k < 4; ++k)
            qa[g][k] = *reinterpret_cast<const f16x8*>(
                Q + (size_t)(n0 + g * 16 + (l & 15)) * FF + k * 32 + (l >> 4) * 8);

    f32x4 U[2][8];
    float mrun[2][4], lrun[2][4];
    #pragma unroll
    for (int g = 0; g < 2; ++g) {
        #pragma unroll
        for (int fb = 0; fb < 8; ++fb) U[g][fb] = f32x4{0.f, 0.f, 0.f, 0.f};
        #pragma unroll
        for (int rg = 0; rg < 4; ++rg) { mrun[g][rg] = -1e30f; lrun[g][rg] = 0.f; }
    }

    int sm = t >> 3, sch = (t & 7) * 8;     // K staging: 32 rows x 128f
    int sf = t >> 2, smm = (t & 3) * 8;     // V staging: 128 rows x 32m

    for (int m0 = 0; m0 < NP; m0 += 32) {
        int4 ka  = *reinterpret_cast<const int4*>(K + (size_t)(m0 + sm) * FF + sch);
        int4 kb2 = *reinterpret_cast<const int4*>(K + (size_t)(m0 + sm) * FF + 64 + sch);
        int4 va  = *reinterpret_cast<const int4*>(V + (size_t)sf * NP + m0 + smm);
        int4 vb2 = *reinterpret_cast<const int4*>(V + (size_t)(sf + 64) * NP + m0 + smm);
        *reinterpret_cast<int4*>(&Klds[sm * 136 + sch]) = ka;
        *reinterpret_cast<int4*>(&Klds[sm * 136 + 64 + sch]) = kb2;
        *reinterpret_cast<int2*>(&Vlds[sf * 40 + smm])            = make_int2(va.x, va.y);
        *reinterpret_cast<int2*>(&Vlds[sf * 40 + smm + 4])        = make_int2(va.z, va.w);
        *reinterpret_cast<int2*>(&Vlds[(sf + 64) * 40 + smm])     = make_int2(vb2.x, vb2.y);
        *reinterpret_cast<int2*>(&Vlds[(sf + 64) * 40 + smm + 4]) = make_int2(vb2.z, vb2.w);
        __syncthreads();

        // S = Q K^T  (rows n, cols m)
        f32x4 S[2][2];
        #pragma unroll
        for (int mc = 0; mc < 2; ++mc) {
            f16x8 kf[4];
            #pragma unroll
            for (int k = 0; k < 4; ++k)
                kf[k] = *reinterpret_cast<const f16x8*>(
                    &Klds[(mc * 16 + (l & 15)) * 136 + k * 32 + (l >> 4) * 8]);
            #pragma unroll
            for (int g = 0; g < 2; ++g) {
                f32x4 s = f32x4{0.f, 0.f, 0.f, 0.f};
                #pragma unroll
                for (int k = 0; k < 4; ++k)
                    s = __builtin_amdgcn_mfma_f32_16x16x32_f16(qa[g][k], kf[k], s, 0, 0, 0);
                S[g][mc] = s;
            }
        }

        // online softmax over the 32 m's of this tile
        #pragma unroll
        for (int g = 0; g < 2; ++g) {
            float sc[4];
            #pragma unroll
            for (int rg = 0; rg < 4; ++rg) {
                float tm = fmaxf(S[g][0][rg], S[g][1][rg]);
                tm = fmaxf(tm, __shfl_xor(tm, 1, 16));
                tm = fmaxf(tm, __shfl_xor(tm, 2, 16));
                tm = fmaxf(tm, __shfl_xor(tm, 4, 16));
                tm = fmaxf(tm, __shfl_xor(tm, 8, 16));
                float mold = mrun[g][rg];
                float mnew = fmaxf(mold, tm);
                float scale = __expf(mold - mnew);
                float p0 = __expf(S[g][0][rg] - mnew);
                float p1 = __expf(S[g][1][rg] - mnew);
                S[g][0][rg] = p0; S[g][1][rg] = p1;
                float rs = p0 + p1;
                rs += __shfl_xor(rs, 1, 16);
                rs += __shfl_xor(rs, 2, 16);
                rs += __shfl_xor(rs, 4, 16);
                rs += __shfl_xor(rs, 8, 16);
                lrun[g][rg] = lrun[g][rg] * scale + rs;
                mrun[g][rg] = mnew;
                sc[rg] = scale;
            }
            #pragma unroll
            for (int fb = 0; fb < 8; ++fb)
                #pragma unroll
                for (int rg = 0; rg < 4; ++rg)
                    U[g][fb][rg] = U[g][fb][rg] * sc[rg];
            #pragma unroll
            for (int mc = 0; mc < 2; ++mc)
                #pragma unroll
                for (int rg = 0; rg < 4; ++rg)
                    Plds[w][(g * 16 + (l >> 4) * 4 + rg) * 40 + mc * 16 + (l & 15)] =
                        f2h(S[g][mc][rg]);
        }

        // U += P V
        f16x8 pa[2];
        #pragma unroll
        for (int g = 0; g < 2; ++g)
            pa[g] = *reinterpret_cast<const f16x8*>(
                &Plds[w][(g * 16 + (l & 15)) * 40 + (l >> 4) * 8]);
        #pragma unroll
        for (int fb = 0; fb < 8; ++fb) {
            f16x8 vf = *reinterpret_cast<const f16x8*>(
                &Vlds[(fb * 16 + (l & 15)) * 40 + (l >> 4) * 8]);
            #pragma unroll
            for (int g = 0; g < 2; ++g)
                U[g][fb] = __builtin_amdgcn_mfma_f32_16x16x32_f16(pa[g], vf, U[g][fb], 0, 0, 0);
        }
        __syncthreads();
    }

    unsigned short* dst = uT + (size_t)b * NP * FF;
    #pragma unroll
    for (int g = 0; g < 2; ++g) {
        float inv[4];
        #pragma unroll
        for (int rg = 0; rg < 4; ++rg) inv[rg] = 1.0f / lrun[g][rg];
        #pragma unroll
        for (int fb = 0; fb < 8; ++fb)
            #pragma unroll
            for (int rg = 0; rg < 4; ++rg) {
                int n = n0 + g * 16 + (l >> 4) * 4 + rg;
                dst[(size_t)n * FF + fb * 16 + (l & 15)] = f2h(U[g][fb][rg] * inv[rg]);
            }
    }
}

// ---------------------------------------------------------------- final gemm + residual + bn + relu
__global__ __launch_bounds__(256) void final_kernel(const unsigned short* __restrict__ uT,
                                                    const unsigned short* __restrict__ W2,
                                                    const float* __restrict__ b2,
                                                    const float* __restrict__ sres,
                                                    const float* __restrict__ x,
                                                    float* __restrict__ out) {
    __shared__ unsigned short Alds[128 * 72];
    __shared__ unsigned short Blds[128 * 72];
    int blk = blockIdx.x;           // 512 = 8 * 2 * 32
    int b  = blk & 7;
    int r  = blk >> 3;
    int ct = r & 1;
    int nt = r >> 1;
    int c0 = ct << 7, n0 = nt << 7;
    int t = threadIdx.x, w = t >> 6, l = t & 63;
    int wr = (w >> 1) << 6, wc = (w & 1) << 6;

    f32x4 acc[4][4];
    #pragma unroll
    for (int i = 0; i < 4; ++i)
        #pragma unroll
        for (int j = 0; j < 4; ++j)
            acc[i][j] = f32x4{0.f, 0.f, 0.f, 0.f};

    for (int k0 = 0; k0 < 128; k0 += 64) {
        #pragma unroll
        for (int i = 0; i < 4; ++i) {
            int row = i * 32 + (t >> 3);
            int ch = (t & 7) * 8;
            *reinterpret_cast<int4*>(&Alds[row * 72 + ch]) =
                *reinterpret_cast<const int4*>(W2 + (size_t)(c0 + row) * FF + k0 + ch);
            *reinterpret_cast<int4*>(&Blds[row * 72 + ch]) =
                *reinterpret_cast<const int4*>(uT + ((size_t)b * NP + n0 + row) * FF + k0 + ch);
        }
        __syncthreads();
        #pragma unroll
        for (int kk = 0; kk < 2; ++kk) {
            f16x8 af[4], bfr[4];
            #pragma unroll
            for (int mi = 0; mi < 4; ++mi)
                af[mi] = *reinterpret_cast<const f16x8*>(
                    &Alds[(wr + mi * 16 + (l & 15)) * 72 + kk * 32 + (l >> 4) * 8]);
            #pragma unroll
            for (int ni = 0; ni < 4; ++ni)
                bfr[ni] = *reinterpret_cast<const f16x8*>(
                    &Blds[(wc + ni * 16 + (l & 15)) * 72 + kk * 32 + (l >> 4) * 8]);
            #pragma unroll
            for (int mi = 0; mi < 4; ++mi)
                #pragma unroll
                for (int ni = 0; ni < 4; ++ni)
                    acc[mi][ni] = __builtin_amdgcn_mfma_f32_16x16x32_f16(af[mi], bfr[ni], acc[mi][ni], 0, 0, 0);
        }
        __syncthreads();
    }

    const float* xb = x + (size_t)b * CC * NP;
    float* ob = out + (size_t)b * CC * NP;
    #pragma unroll
    for (int mi = 0; mi < 4; ++mi)
        #pragma unroll
        for (int ni = 0; ni < 4; ++ni) {
            int n = n0 + wc + ni * 16 + (l & 15);
            int cb = c0 + wr + mi * 16 + ((l >> 4) << 2);
            #pragma unroll
            for (int rg = 0; rg < 4; ++rg) {
                int c = cb + rg;
                float v = acc[mi][ni][rg] + b2[c] + sres[c] * xb[(size_t)c * NP + n];
                ob[(size_t)c * NP + n] = v > 0.f ? v : 0.f;
            }
        }
}

// ---------------------------------------------------------------- launch
extern "C" void kernel_launch(void* const* d_in, const int* in_sizes, int n_in,
                              void* d_out, int out_size, void* d_ws, size_t ws_size,
                              hipStream_t stream) {
    const float* x = (const float*)d_in[0];
    char* ws = (char*)d_ws;
    // ws layout (bytes)
    unsigned short* W_all = (unsigned short*)(ws);                    // 384*256*2   = 196608
    float*          b_all = (float*)(ws + 196608);                    // 384*4       = 1536
    unsigned short* W2    = (unsigned short*)(ws + 198144);           // 256*128*2   = 65536
    float*          b2    = (float*)(ws + 263680);                    // 256*4
    float*          sres  = (float*)(ws + 264704);                    // 256*4
    unsigned short* xT    = (unsigned short*)(ws + 265728);           // 8*4096*256*2 = 16777216
    unsigned short* tq    = (unsigned short*)(ws + 17042944);         // 8*4096*128*2 = 8388608
    unsigned short* kp    = (unsigned short*)(ws + 25431552);
    unsigned short* vz    = (unsigned short*)(ws + 33820160);
    unsigned short* uT    = (unsigned short*)(ws + 42208768);         // end 50597376

    PrepArgs pa;
    pa.w[0]  = (const float*)d_in[1];  pa.bias[0] = (const float*)d_in[2];
    pa.g[0]  = (const float*)d_in[3];  pa.be[0]   = (const float*)d_in[4];
    pa.m[0]  = (const float*)d_in[5];  pa.v[0]    = (const float*)d_in[6];
    pa.w[1]  = (const float*)d_in[7];  pa.bias[1] = (const float*)d_in[8];
    pa.g[1]  = (const float*)d_in[9];  pa.be[1]   = (const float*)d_in[10];
    pa.m[1]  = (const float*)d_in[11]; pa.v[1]    = (const float*)d_in[12];
    pa.w[2]  = (const float*)d_in[13]; pa.bias[2] = (const float*)d_in[14];
    pa.g[2]  = (const float*)d_in[15]; pa.be[2]   = (const float*)d_in[16];
    pa.m[2]  = (const float*)d_in[17]; pa.v[2]    = (const float*)d_in[18];
    pa.pre_w = (const float*)d_in[19]; pa.pre_b   = (const float*)d_in[20];
    pa.post_g = (const float*)d_in[21]; pa.post_be = (const float*)d_in[22];
    pa.post_m = (const float*)d_in[23]; pa.post_v  = (const float*)d_in[24];
    pa.W_all = W_all; pa.b_all = b_all; pa.W2 = W2; pa.b2 = b2; pa.sres = sres;

    prep_kernel<<<dim3(512), dim3(256), 0, stream>>>(pa);
    transpose_x_kernel<<<dim3(2048), dim3(256), 0, stream>>>(x, xT);
    qkv_kernel<<<dim3(768), dim3(256), 0, stream>>>(xT, W_all, b_all, tq, kp, vz);
    attn_kernel<<<dim3(256), dim3(256), 0, stream>>>(tq, kp, vz, uT);
    final_kernel<<<dim3(512), dim3(256), 0, stream>>>(uT, W2, b2, sres, x, (float*)d_out);
}

// Round 2
// 274.105 us; speedup vs baseline: 1.6308x; 1.6308x over previous
//
#include <hip/hip_runtime.h>

typedef __attribute__((ext_vector_type(8))) _Float16 f16x8;
typedef __attribute__((ext_vector_type(4))) float f32x4;

#define EPSV 1e-5f
#define BB 8
#define CC 256
#define NP 4096
#define FF 128
#define SPLIT 4
#define CHUNK 1024

static __device__ __forceinline__ unsigned short f2h(float f) {
    union { _Float16 h; unsigned short u; } v;
    v.h = (_Float16)f;
    return v.u;
}
static __device__ __forceinline__ float h2f(unsigned short u) {
    union { unsigned short u; _Float16 h; } v;
    v.u = u;
    return (float)v.h;
}

// ---------------------------------------------------------------- prep
struct PrepArgs {
    const float* w[3]; const float* bias[3]; const float* g[3]; const float* be[3];
    const float* m[3]; const float* v[3];
    const float* pre_w; const float* pre_b;
    const float* post_g; const float* post_be; const float* post_m; const float* post_v;
    unsigned short* W_all; float* b_all; unsigned short* W2; float* b2; float* sres;
};

__global__ __launch_bounds__(256) void prep_kernel(PrepArgs a) {
    int idx = blockIdx.x * 256 + threadIdx.x;
    if (idx < 3 * 128 * 256) {
        int row = idx >> 8, c = idx & 255;
        int which = row >> 7, f = row & 127;
        float s = a.g[which][f] * rsqrtf(a.v[which][f] + EPSV);
        a.W_all[idx] = f2h(a.w[which][f * 256 + c] * s);
        if (c == 0)
            a.b_all[row] = s * a.bias[which][f] + a.be[which][f] - a.m[which][f] * s;
    } else {
        int i = idx - 3 * 128 * 256;
        if (i < 256 * 128) {
            int c = i >> 7, f = i & 127;
            float s = a.post_g[c] * rsqrtf(a.post_v[c] + EPSV);
            a.W2[i] = f2h(a.pre_w[i] * s);
            if (f == 0) {
                a.b2[c] = s * a.pre_b[c] + a.post_be[c] - a.post_m[c] * s;
                a.sres[c] = s;
            }
        }
    }
}

// ---------------------------------------------------------------- transpose x -> xT f16
__global__ __launch_bounds__(256) void transpose_x_kernel(const float* __restrict__ x,
                                                          unsigned short* __restrict__ xT) {
    __shared__ float tile[64][65];
    int blk = blockIdx.x;           // 8 * 4 * 64
    int b  = blk >> 8;
    int c0 = ((blk >> 6) & 3) << 6;
    int n0 = (blk & 63) << 6;
    int t = threadIdx.x;
    const float* src = x + ((size_t)b * CC + c0) * NP + n0;
    #pragma unroll
    for (int i = 0; i < 16; ++i) {
        int cl = i * 4 + (t >> 6);
        tile[cl][t & 63] = src[(size_t)cl * NP + (t & 63)];
    }
    __syncthreads();
    unsigned short* dst = xT + ((size_t)b * NP + n0) * CC + c0;
    #pragma unroll
    for (int i = 0; i < 8; ++i) {
        int nl = i * 8 + (t >> 5);
        int cl = (t & 31) * 2;
        unsigned lo = f2h(tile[cl][nl]);
        unsigned hi = f2h(tile[cl + 1][nl]);
        *reinterpret_cast<unsigned*>(dst + (size_t)nl * CC + cl) = (hi << 16) | lo;
    }
}

// ---------------------------------------------------------------- qkv gemm
__global__ __launch_bounds__(256) void qkv_kernel(const unsigned short* __restrict__ xT,
                                                  const unsigned short* __restrict__ W_all,
                                                  const float* __restrict__ b_all,
                                                  unsigned short* __restrict__ tq,
                                                  unsigned short* __restrict__ kp,
                                                  unsigned short* __restrict__ vz) {
    __shared__ unsigned short Alds[128 * 72];
    __shared__ unsigned short Blds[128 * 72];
    int blk = blockIdx.x;           // 768 = 8 batches * 3 ftiles * 32 ntiles
    int b  = blk & 7;               // XCD-affine batch
    int r  = blk >> 3;              // 0..95
    int ft = r >> 5;                // 0..2
    int n0 = (r & 31) << 7;
    int fbase = ft << 7;
    int t = threadIdx.x, w = t >> 6, l = t & 63;
    int wr = (w >> 1) << 6, wc = (w & 1) << 6;
    const unsigned short* A  = xT + ((size_t)b * NP + n0) * CC;
    const unsigned short* Bw = W_all + (size_t)fbase * CC;

    f32x4 acc[4][4];
    #pragma unroll
    for (int i = 0; i < 4; ++i)
        #pragma unroll
        for (int j = 0; j < 4; ++j)
            acc[i][j] = f32x4{0.f, 0.f, 0.f, 0.f};

    for (int c0 = 0; c0 < 256; c0 += 64) {
        #pragma unroll
        for (int i = 0; i < 4; ++i) {
            int row = i * 32 + (t >> 3);
            int ch = (t & 7) * 8;
            *reinterpret_cast<int4*>(&Alds[row * 72 + ch]) =
                *reinterpret_cast<const int4*>(A + (size_t)row * CC + c0 + ch);
            *reinterpret_cast<int4*>(&Blds[row * 72 + ch]) =
                *reinterpret_cast<const int4*>(Bw + (size_t)row * CC + c0 + ch);
        }
        __syncthreads();
        #pragma unroll
        for (int kk = 0; kk < 2; ++kk) {
            f16x8 af[4], bfr[4];
            #pragma unroll
            for (int mi = 0; mi < 4; ++mi)
                af[mi] = *reinterpret_cast<const f16x8*>(
                    &Alds[(wr + mi * 16 + (l & 15)) * 72 + kk * 32 + (l >> 4) * 8]);
            #pragma unroll
            for (int ni = 0; ni < 4; ++ni)
                bfr[ni] = *reinterpret_cast<const f16x8*>(
                    &Blds[(wc + ni * 16 + (l & 15)) * 72 + kk * 32 + (l >> 4) * 8]);
            #pragma unroll
            for (int mi = 0; mi < 4; ++mi)
                #pragma unroll
                for (int ni = 0; ni < 4; ++ni)
                    acc[mi][ni] = __builtin_amdgcn_mfma_f32_16x16x32_f16(af[mi], bfr[ni], acc[mi][ni], 0, 0, 0);
        }
        __syncthreads();
    }

    #pragma unroll
    for (int mi = 0; mi < 4; ++mi) {
        #pragma unroll
        for (int ni = 0; ni < 4; ++ni) {
            int fl = wc + ni * 16 + (l & 15);
            float bias = b_all[fbase + fl];
            int nb = n0 + wr + mi * 16 + ((l >> 4) << 2);
            if (ft == 2) {
                unsigned pk0, pk1;
                float v0 = acc[mi][ni][0] + bias; v0 = v0 > 0.f ? v0 : 0.f;
                float v1 = acc[mi][ni][1] + bias; v1 = v1 > 0.f ? v1 : 0.f;
                float v2 = acc[mi][ni][2] + bias; v2 = v2 > 0.f ? v2 : 0.f;
                float v3 = acc[mi][ni][3] + bias; v3 = v3 > 0.f ? v3 : 0.f;
                pk0 = (unsigned)f2h(v0) | ((unsigned)f2h(v1) << 16);
                pk1 = (unsigned)f2h(v2) | ((unsigned)f2h(v3) << 16);
                uint2 uu; uu.x = pk0; uu.y = pk1;
                *reinterpret_cast<uint2*>(vz + (size_t)b * FF * NP + (size_t)fl * NP + nb) = uu;
            } else {
                unsigned short* dst = (ft == 0 ? tq : kp) + (size_t)b * NP * FF;
                #pragma unroll
                for (int rg = 0; rg < 4; ++rg) {
                    float v = acc[mi][ni][rg] + bias;
                    dst[(size_t)(nb + rg) * FF + fl] = f2h(v > 0.f ? v : 0.f);
                }
            }
        }
    }
}

// ---------------------------------------------------------------- flash attention, split-KV x4
// Swapped QK^T: S^T = mfma(K_frag, Q_frag) -> per lane, row-softmax is reg-local + 2 shfl.
// Each block: 128 Q rows x 1024-KV chunk; partials (normalized f16 U, and m,l) to ws.
__global__ __launch_bounds__(256, 4) void attn_kernel(const unsigned short* __restrict__ tq,
                                                      const unsigned short* __restrict__ kp,
                                                      const unsigned short* __restrict__ vz,
                                                      unsigned short* __restrict__ Uh,
                                                      float2* __restrict__ ml) {
    __shared__ unsigned short Klds[32 * 136];
    __shared__ unsigned short Vlds[128 * 40];
    __shared__ unsigned short Plds[4][32 * 40];
    int blk = blockIdx.x;            // 1024 = 8 b * (32 qt * 4 s)
    int b = blk & 7;                 // XCD-affine batch
    int rest = blk >> 3;             // 0..127
    int s = rest & 3;
    int qt = rest >> 2;              // 0..31
    int t = threadIdx.x, w = t >> 6, l = t & 63;
    int n0 = qt * 128 + w * 32;
    int mbase = s * CHUNK;
    const unsigned short* Q = tq + (size_t)b * NP * FF;
    const unsigned short* K = kp + (size_t)b * NP * FF;
    const unsigned short* V = vz + (size_t)b * FF * NP;

    f16x8 qa[2][4];
    #pragma unroll
    for (int g = 0; g < 2; ++g)
        #pragma unroll
        for (int kk = 0; kk < 4; ++kk)
            qa[g][kk] = *reinterpret_cast<const f16x8*>(
                Q + (size_t)(n0 + g * 16 + (l & 15)) * FF + kk * 32 + (l >> 4) * 8);

    f32x4 U[2][8];
    float mrun[2], lrun[2];
    #pragma unroll
    for (int g = 0; g < 2; ++g) {
        #pragma unroll
        for (int fb = 0; fb < 8; ++fb) U[g][fb] = f32x4{0.f, 0.f, 0.f, 0.f};
        mrun[g] = -1e30f; lrun[g] = 0.f;
    }

    int sm = t >> 3, sch = (t & 7) * 8;     // K staging: 32 rows x 128f
    int sf = t >> 2, smm = (t & 3) * 8;     // V staging: 128 rows x 32m

    for (int it = 0; it < CHUNK / 32; ++it) {
        int m0 = mbase + it * 32;
        int4 ka  = *reinterpret_cast<const int4*>(K + (size_t)(m0 + sm) * FF + sch);
        int4 kb2 = *reinterpret_cast<const int4*>(K + (size_t)(m0 + sm) * FF + 64 + sch);
        int4 va  = *reinterpret_cast<const int4*>(V + (size_t)sf * NP + m0 + smm);
        int4 vb2 = *reinterpret_cast<const int4*>(V + (size_t)(sf + 64) * NP + m0 + smm);
        *reinterpret_cast<int4*>(&Klds[sm * 136 + sch]) = ka;
        *reinterpret_cast<int4*>(&Klds[sm * 136 + 64 + sch]) = kb2;
        *reinterpret_cast<int2*>(&Vlds[sf * 40 + smm])            = make_int2(va.x, va.y);
        *reinterpret_cast<int2*>(&Vlds[sf * 40 + smm + 4])        = make_int2(va.z, va.w);
        *reinterpret_cast<int2*>(&Vlds[(sf + 64) * 40 + smm])     = make_int2(vb2.x, vb2.y);
        *reinterpret_cast<int2*>(&Vlds[(sf + 64) * 40 + smm + 4]) = make_int2(vb2.z, vb2.w);
        __syncthreads();

        // S^T = K Q^T : rows m (regs), cols n (lane&15)
        f32x4 St[2][2];     // [mt][g]
        #pragma unroll
        for (int mt = 0; mt < 2; ++mt) {
            St[mt][0] = f32x4{0.f, 0.f, 0.f, 0.f};
            St[mt][1] = f32x4{0.f, 0.f, 0.f, 0.f};
        }
        __builtin_amdgcn_s_setprio(1);
        #pragma unroll
        for (int mt = 0; mt < 2; ++mt)
            #pragma unroll
            for (int kk = 0; kk < 4; ++kk) {
                f16x8 kf = *reinterpret_cast<const f16x8*>(
                    &Klds[(mt * 16 + (l & 15)) * 136 + kk * 32 + (l >> 4) * 8]);
                St[mt][0] = __builtin_amdgcn_mfma_f32_16x16x32_f16(kf, qa[0][kk], St[mt][0], 0, 0, 0);
                St[mt][1] = __builtin_amdgcn_mfma_f32_16x16x32_f16(kf, qa[1][kk], St[mt][1], 0, 0, 0);
            }
        __builtin_amdgcn_s_setprio(0);

        // online softmax: per lane, n = g*16 + (l&15); m-values live in regs (8) + quarters
        #pragma unroll
        for (int g = 0; g < 2; ++g) {
            float pmax = St[0][g][0];
            pmax = fmaxf(pmax, St[0][g][1]); pmax = fmaxf(pmax, St[0][g][2]);
            pmax = fmaxf(pmax, St[0][g][3]); pmax = fmaxf(pmax, St[1][g][0]);
            pmax = fmaxf(pmax, St[1][g][1]); pmax = fmaxf(pmax, St[1][g][2]);
            pmax = fmaxf(pmax, St[1][g][3]);
            pmax = fmaxf(pmax, __shfl_xor(pmax, 16));
            pmax = fmaxf(pmax, __shfl_xor(pmax, 32));
            if (__any(pmax > mrun[g] + 8.0f)) {       // defer-max, THR=8
                float mnew = fmaxf(mrun[g], pmax);
                float sc = __expf(mrun[g] - mnew);
                mrun[g] = mnew;
                lrun[g] *= sc;
                #pragma unroll
                for (int rg = 0; rg < 4; ++rg) {
                    float scu = __shfl(sc, ((l >> 4) << 2) | rg);
                    #pragma unroll
                    for (int fb = 0; fb < 8; ++fb) U[g][fb][rg] *= scu;
                }
            }
            float lsum = 0.f;
            #pragma unroll
            for (int mt = 0; mt < 2; ++mt)
                #pragma unroll
                for (int rg = 0; rg < 4; ++rg) {
                    float p = __expf(St[mt][g][rg] - mrun[g]);
                    St[mt][g][rg] = p;
                    lsum += p;
                }
            lsum += __shfl_xor(lsum, 16);
            lsum += __shfl_xor(lsum, 32);
            lrun[g] += lsum;
            #pragma unroll
            for (int mt = 0; mt < 2; ++mt) {
                unsigned p01 = (unsigned)f2h(St[mt][g][0]) | ((unsigned)f2h(St[mt][g][1]) << 16);
                unsigned p23 = (unsigned)f2h(St[mt][g][2]) | ((unsigned)f2h(St[mt][g][3]) << 16);
                int base = (g * 16 + (l & 15)) * 40 + mt * 16 + ((l >> 4) << 2);
                *reinterpret_cast<unsigned*>(&Plds[w][base])     = p01;
                *reinterpret_cast<unsigned*>(&Plds[w][base + 2]) = p23;
            }
        }

        // U += P V
        f16x8 pa[2];
        #pragma unroll
        for (int g = 0; g < 2; ++g)
            pa[g] = *reinterpret_cast<const f16x8*>(
                &Plds[w][(g * 16 + (l & 15)) * 40 + (l >> 4) * 8]);
        __builtin_amdgcn_s_setprio(1);
        #pragma unroll
        for (int fb = 0; fb < 8; ++fb) {
            f16x8 vf = *reinterpret_cast<const f16x8*>(
                &Vlds[(fb * 16 + (l & 15)) * 40 + (l >> 4) * 8]);
            U[0][fb] = __builtin_amdgcn_mfma_f32_16x16x32_f16(pa[0], vf, U[0][fb], 0, 0, 0);
            U[1][fb] = __builtin_amdgcn_mfma_f32_16x16x32_f16(pa[1], vf, U[1][fb], 0, 0, 0);
        }
        __builtin_amdgcn_s_setprio(0);
        __syncthreads();
    }

    // partials: Uh[s][b][n][f] = U/l (f16), ml[s][b][n] = (m, l)
    unsigned short* up = Uh + (size_t)(s * 8 + b) * NP * FF;
    #pragma unroll
    for (int g = 0; g < 2; ++g) {
        float linv = 1.0f / lrun[g];
        #pragma unroll
        for (int rg = 0; rg < 4; ++rg) {
            float li = __shfl(linv, ((l >> 4) << 2) | rg);
            int n = n0 + g * 16 + ((l >> 4) << 2) + rg;
            #pragma unroll
            for (int fb = 0; fb < 8; ++fb)
                up[(size_t)n * FF + fb * 16 + (l & 15)] = f2h(U[g][fb][rg] * li);
        }
    }
    if (l < 16) {
        ml[(size_t)(s * 8 + b) * NP + n0 + l]      = make_float2(mrun[0], lrun[0]);
        ml[(size_t)(s * 8 + b) * NP + n0 + 16 + l] = make_float2(mrun[1], lrun[1]);
    }
}

// ---------------------------------------------------------------- combine split-KV partials
__global__ __launch_bounds__(256) void combine_kernel(const unsigned short* __restrict__ Uh,
                                                      const float2* __restrict__ ml,
                                                      unsigned short* __restrict__ uT) {
    int row = blockIdx.x * 2 + (threadIdx.x >> 7);   // b*4096 + n
    int f = threadIdx.x & 127;
    float m[SPLIT], lv[SPLIT];
    #pragma unroll
    for (int s = 0; s < SPLIT; ++s) {
        float2 v = ml[(size_t)s * (BB * NP) + row];
        m[s] = v.x; lv[s] = v.y;
    }
    float M = fmaxf(fmaxf(m[0], m[1]), fmaxf(m[2], m[3]));
    float wsum = 0.f, acc = 0.f;
    #pragma unroll
    for (int s = 0; s < SPLIT; ++s) {
        float wgt = __expf(m[s] - M) * lv[s];
        wsum += wgt;
        acc += wgt * h2f(Uh[((size_t)s * (BB * NP) + row) * FF + f]);
    }
    uT[(size_t)row * FF + f] = f2h(acc / wsum);
}

// ---------------------------------------------------------------- final gemm + residual + bn + relu
__global__ __launch_bounds__(256) void final_kernel(const unsigned short* __restrict__ uT,
                                                    const unsigned short* __restrict__ W2,
                                                    const float* __restrict__ b2,
                                                    const float* __restrict__ sres,
                                                    const float* __restrict__ x,
                                                    float* __restrict__ out) {
    __shared__ unsigned short Alds[128 * 72];
    __shared__ unsigned short Blds[128 * 72];
    int blk = blockIdx.x;           // 512 = 8 * 2 * 32
    int b  = blk & 7;
    int r  = blk >> 3;
    int ct = r & 1;
    int nt = r >> 1;
    int c0 = ct << 7, n0 = nt << 7;
    int t = threadIdx.x, w = t >> 6, l = t & 63;
    int wr = (w >> 1) << 6, wc = (w & 1) << 6;

    f32x4 acc[4][4];
    #pragma unroll
    for (int i = 0; i < 4; ++i)
        #pragma unroll
        for (int j = 0; j < 4; ++j)
            acc[i][j] = f32x4{0.f, 0.f, 0.f, 0.f};

    for (int k0 = 0; k0 < 128; k0 += 64) {
        #pragma unroll
        for (int i = 0; i < 4; ++i) {
            int row = i * 32 + (t >> 3);
            int ch = (t & 7) * 8;
            *reinterpret_cast<int4*>(&Alds[row * 72 + ch]) =
                *reinterpret_cast<const int4*>(W2 + (size_t)(c0 + row) * FF + k0 + ch);
            *reinterpret_cast<int4*>(&Blds[row * 72 + ch]) =
                *reinterpret_cast<const int4*>(uT + ((size_t)b * NP + n0 + row) * FF + k0 + ch);
        }
        __syncthreads();
        #pragma unroll
        for (int kk = 0; kk < 2; ++kk) {
            f16x8 af[4], bfr[4];
            #pragma unroll
            for (int mi = 0; mi < 4; ++mi)
                af[mi] = *reinterpret_cast<const f16x8*>(
                    &Alds[(wr + mi * 16 + (l & 15)) * 72 + kk * 32 + (l >> 4) * 8]);
            #pragma unroll
            for (int ni = 0; ni < 4; ++ni)
                bfr[ni] = *reinterpret_cast<const f16x8*>(
                    &Blds[(wc + ni * 16 + (l & 15)) * 72 + kk * 32 + (l >> 4) * 8]);
            #pragma unroll
            for (int mi = 0; mi < 4; ++mi)
                #pragma unroll
                for (int ni = 0; ni < 4; ++ni)
                    acc[mi][ni] = __builtin_amdgcn_mfma_f32_16x16x32_f16(af[mi], bfr[ni], acc[mi][ni], 0, 0, 0);
        }
        __syncthreads();
    }

    const float* xb = x + (size_t)b * CC * NP;
    float* ob = out + (size_t)b * CC * NP;
    #pragma unroll
    for (int mi = 0; mi < 4; ++mi)
        #pragma unroll
        for (int ni = 0; ni < 4; ++ni) {
            int n = n0 + wc + ni * 16 + (l & 15);
            int cb = c0 + wr + mi * 16 + ((l >> 4) << 2);
            #pragma unroll
            for (int rg = 0; rg < 4; ++rg) {
                int c = cb + rg;
                float v = acc[mi][ni][rg] + b2[c] + sres[c] * xb[(size_t)c * NP + n];
                ob[(size_t)c * NP + n] = v > 0.f ? v : 0.f;
            }
        }
}

// ---------------------------------------------------------------- launch
extern "C" void kernel_launch(void* const* d_in, const int* in_sizes, int n_in,
                              void* d_out, int out_size, void* d_ws, size_t ws_size,
                              hipStream_t stream) {
    const float* x = (const float*)d_in[0];
    char* ws = (char*)d_ws;
    // ws layout (bytes)
    unsigned short* W_all = (unsigned short*)(ws);                    // 384*256*2   = 196608
    float*          b_all = (float*)(ws + 196608);                    // 384*4
    unsigned short* W2    = (unsigned short*)(ws + 198144);           // 256*128*2
    float*          b2    = (float*)(ws + 263680);
    float*          sres  = (float*)(ws + 264704);
    unsigned short* xT    = (unsigned short*)(ws + 265728);           // 8*4096*256*2 = 16777216
    unsigned short* tq    = (unsigned short*)(ws + 17042944);         // 8*4096*128*2 = 8388608
    unsigned short* kp    = (unsigned short*)(ws + 25431552);
    unsigned short* vz    = (unsigned short*)(ws + 33820160);
    unsigned short* uT    = (unsigned short*)(ws + 42208768);
    unsigned short* Uh    = (unsigned short*)(ws + 50597376);         // 4*8*4096*128*2 = 33554432
    float2*         ml    = (float2*)(ws + 84151808);                 // 4*8*4096*8 = 1048576
    // end 85200384

    PrepArgs pa;
    pa.w[0]  = (const float*)d_in[1];  pa.bias[0] = (const float*)d_in[2];
    pa.g[0]  = (const float*)d_in[3];  pa.be[0]   = (const float*)d_in[4];
    pa.m[0]  = (const float*)d_in[5];  pa.v[0]    = (const float*)d_in[6];
    pa.w[1]  = (const float*)d_in[7];  pa.bias[1] = (const float*)d_in[8];
    pa.g[1]  = (const float*)d_in[9];  pa.be[1]   = (const float*)d_in[10];
    pa.m[1]  = (const float*)d_in[11]; pa.v[1]    = (const float*)d_in[12];
    pa.w[2]  = (const float*)d_in[13]; pa.bias[2] = (const float*)d_in[14];
    pa.g[2]  = (const float*)d_in[15]; pa.be[2]   = (const float*)d_in[16];
    pa.m[2]  = (const float*)d_in[17]; pa.v[2]    = (const float*)d_in[18];
    pa.pre_w = (const float*)d_in[19]; pa.pre_b   = (const float*)d_in[20];
    pa.post_g = (const float*)d_in[21]; pa.post_be = (const float*)d_in[22];
    pa.post_m = (const float*)d_in[23]; pa.post_v  = (const float*)d_in[24];
    pa.W_all = W_all; pa.b_all = b_all; pa.W2 = W2; pa.b2 = b2; pa.sres = sres;

    prep_kernel<<<dim3(512), dim3(256), 0, stream>>>(pa);
    transpose_x_kernel<<<dim3(2048), dim3(256), 0, stream>>>(x, xT);
    qkv_kernel<<<dim3(768), dim3(256), 0, stream>>>(xT, W_all, b_all, tq, kp, vz);
    attn_kernel<<<dim3(1024), dim3(256), 0, stream>>>(tq, kp, vz, Uh, ml);
    combine_kernel<<<dim3(16384), dim3(256), 0, stream>>>(Uh, ml, uT);
    final_kernel<<<dim3(512), dim3(256), 0, stream>>>(uT, W2, b2, sres, x, (float*)d_out);
}

// Round 3
// 266.214 us; speedup vs baseline: 1.6792x; 1.0296x over previous
//
#include <hip/hip_runtime.h>

typedef __attribute__((ext_vector_type(8))) _Float16 f16x8;
typedef __attribute__((ext_vector_type(4))) float f32x4;
typedef __attribute__((ext_vector_type(16))) float f32x16;
typedef __attribute__((ext_vector_type(4))) unsigned u32x4;

#define EPSV 1e-5f
#define BB 8
#define CC 256
#define NP 4096
#define FF 128
#define SPLIT 4
#define CHUNK 1024
#define NIT 16

#define GLD16(gp, lp) __builtin_amdgcn_global_load_lds( \
    (const __attribute__((address_space(1))) unsigned int*)(gp), \
    (__attribute__((address_space(3))) unsigned int*)(lp), 16, 0, 0)

static __device__ __forceinline__ unsigned short f2h(float f) {
    union { _Float16 h; unsigned short u; } v;
    v.h = (_Float16)f;
    return v.u;
}
static __device__ __forceinline__ float h2f(unsigned short u) {
    union { unsigned short u; _Float16 h; } v;
    v.u = u;
    return (float)v.h;
}

// ---------------------------------------------------------------- prep
struct PrepArgs {
    const float* w[3]; const float* bias[3]; const float* g[3]; const float* be[3];
    const float* m[3]; const float* v[3];
    const float* pre_w; const float* pre_b;
    const float* post_g; const float* post_be; const float* post_m; const float* post_v;
    unsigned short* W_all; float* b_all; unsigned short* W2; float* b2; float* sres;
};

__global__ __launch_bounds__(256) void prep_kernel(PrepArgs a) {
    int idx = blockIdx.x * 256 + threadIdx.x;
    if (idx < 3 * 128 * 256) {
        int row = idx >> 8, c = idx & 255;
        int which = row >> 7, f = row & 127;
        float s = a.g[which][f] * rsqrtf(a.v[which][f] + EPSV);
        a.W_all[idx] = f2h(a.w[which][f * 256 + c] * s);
        if (c == 0)
            a.b_all[row] = s * a.bias[which][f] + a.be[which][f] - a.m[which][f] * s;
    } else {
        int i = idx - 3 * 128 * 256;
        if (i < 256 * 128) {
            int c = i >> 7, f = i & 127;
            float s = a.post_g[c] * rsqrtf(a.post_v[c] + EPSV);
            a.W2[i] = f2h(a.pre_w[i] * s);
            if (f == 0) {
                a.b2[c] = s * a.pre_b[c] + a.post_be[c] - a.post_m[c] * s;
                a.sres[c] = s;
            }
        }
    }
}

// ---------------------------------------------------------------- transpose x -> xT f16
__global__ __launch_bounds__(256) void transpose_x_kernel(const float* __restrict__ x,
                                                          unsigned short* __restrict__ xT) {
    __shared__ float tile[64][65];
    int blk = blockIdx.x;           // 8 * 4 * 64
    int b  = blk >> 8;
    int c0 = ((blk >> 6) & 3) << 6;
    int n0 = (blk & 63) << 6;
    int t = threadIdx.x;
    const float* src = x + ((size_t)b * CC + c0) * NP + n0;
    #pragma unroll
    for (int i = 0; i < 16; ++i) {
        int cl = i * 4 + (t >> 6);
        tile[cl][t & 63] = src[(size_t)cl * NP + (t & 63)];
    }
    __syncthreads();
    unsigned short* dst = xT + ((size_t)b * NP + n0) * CC + c0;
    #pragma unroll
    for (int i = 0; i < 8; ++i) {
        int nl = i * 8 + (t >> 5);
        int cl = (t & 31) * 2;
        unsigned lo = f2h(tile[cl][nl]);
        unsigned hi = f2h(tile[cl + 1][nl]);
        *reinterpret_cast<unsigned*>(dst + (size_t)nl * CC + cl) = (hi << 16) | lo;
    }
}

// ---------------------------------------------------------------- qkv gemm
__global__ __launch_bounds__(256) void qkv_kernel(const unsigned short* __restrict__ xT,
                                                  const unsigned short* __restrict__ W_all,
                                                  const float* __restrict__ b_all,
                                                  unsigned short* __restrict__ tq,
                                                  unsigned short* __restrict__ kp,
                                                  unsigned short* __restrict__ vz) {
    __shared__ unsigned short Alds[128 * 72];
    __shared__ unsigned short Blds[128 * 72];
    int blk = blockIdx.x;           // 768 = 8 batches * 3 ftiles * 32 ntiles
    int b  = blk & 7;               // XCD-affine batch
    int r  = blk >> 3;              // 0..95
    int ft = r >> 5;                // 0..2
    int n0 = (r & 31) << 7;
    int fbase = ft << 7;
    int t = threadIdx.x, w = t >> 6, l = t & 63;
    int wr = (w >> 1) << 6, wc = (w & 1) << 6;
    const unsigned short* A  = xT + ((size_t)b * NP + n0) * CC;
    const unsigned short* Bw = W_all + (size_t)fbase * CC;

    f32x4 acc[4][4];
    #pragma unroll
    for (int i = 0; i < 4; ++i)
        #pragma unroll
        for (int j = 0; j < 4; ++j)
            acc[i][j] = f32x4{0.f, 0.f, 0.f, 0.f};

    for (int c0 = 0; c0 < 256; c0 += 64) {
        #pragma unroll
        for (int i = 0; i < 4; ++i) {
            int row = i * 32 + (t >> 3);
            int ch = (t & 7) * 8;
            *reinterpret_cast<int4*>(&Alds[row * 72 + ch]) =
                *reinterpret_cast<const int4*>(A + (size_t)row * CC + c0 + ch);
            *reinterpret_cast<int4*>(&Blds[row * 72 + ch]) =
                *reinterpret_cast<const int4*>(Bw + (size_t)row * CC + c0 + ch);
        }
        __syncthreads();
        #pragma unroll
        for (int kk = 0; kk < 2; ++kk) {
            f16x8 af[4], bfr[4];
            #pragma unroll
            for (int mi = 0; mi < 4; ++mi)
                af[mi] = *reinterpret_cast<const f16x8*>(
                    &Alds[(wr + mi * 16 + (l & 15)) * 72 + kk * 32 + (l >> 4) * 8]);
            #pragma unroll
            for (int ni = 0; ni < 4; ++ni)
                bfr[ni] = *reinterpret_cast<const f16x8*>(
                    &Blds[(wc + ni * 16 + (l & 15)) * 72 + kk * 32 + (l >> 4) * 8]);
            #pragma unroll
            for (int mi = 0; mi < 4; ++mi)
                #pragma unroll
                for (int ni = 0; ni < 4; ++ni)
                    acc[mi][ni] = __builtin_amdgcn_mfma_f32_16x16x32_f16(af[mi], bfr[ni], acc[mi][ni], 0, 0, 0);
        }
        __syncthreads();
    }

    #pragma unroll
    for (int mi = 0; mi < 4; ++mi) {
        #pragma unroll
        for (int ni = 0; ni < 4; ++ni) {
            int fl = wc + ni * 16 + (l & 15);
            float bias = b_all[fbase + fl];
            int nb = n0 + wr + mi * 16 + ((l >> 4) << 2);
            if (ft == 2) {
                unsigned pk0, pk1;
                float v0 = acc[mi][ni][0] + bias; v0 = v0 > 0.f ? v0 : 0.f;
                float v1 = acc[mi][ni][1] + bias; v1 = v1 > 0.f ? v1 : 0.f;
                float v2 = acc[mi][ni][2] + bias; v2 = v2 > 0.f ? v2 : 0.f;
                float v3 = acc[mi][ni][3] + bias; v3 = v3 > 0.f ? v3 : 0.f;
                pk0 = (unsigned)f2h(v0) | ((unsigned)f2h(v1) << 16);
                pk1 = (unsigned)f2h(v2) | ((unsigned)f2h(v3) << 16);
                uint2 uu; uu.x = pk0; uu.y = pk1;
                *reinterpret_cast<uint2*>(vz + (size_t)b * FF * NP + (size_t)fl * NP + nb) = uu;
            } else {
                unsigned short* dst = (ft == 0 ? tq : kp) + (size_t)b * NP * FF;
                #pragma unroll
                for (int rg = 0; rg < 4; ++rg) {
                    float v = acc[mi][ni][rg] + bias;
                    dst[(size_t)(nb + rg) * FF + fl] = f2h(v > 0.f ? v : 0.f);
                }
            }
        }
    }
}

// ---------------------------------------------------------------- flash attention, split-KV x4
// 32x32 MFMA; swapped QK^T (S^T = K Q^T); softmax fully in-register (1 shfl_xor max, 1 sum);
// P->PV A-frag rebuilt in-register via cvt_pkrtz + cross-half shfl; K/V staged via
// global_load_lds into XOR-swizzled LDS (pre-swizzled global source, swizzled read),
// double-buffered with one barrier per KV tile.
__global__ __launch_bounds__(256, 2) void attn_kernel(const unsigned short* __restrict__ tq,
                                                      const unsigned short* __restrict__ kp,
                                                      const unsigned short* __restrict__ vz,
                                                      unsigned short* __restrict__ Uh,
                                                      float2* __restrict__ ml) {
    __shared__ unsigned short Kl[2][8192];   // [buf][m 64][f 128], slot-swizzled (slot ^= m&7)
    __shared__ unsigned short Vl[2][8192];   // [buf][f 128][m 64], slot-swizzled (slot ^= f&7)
    int blk = blockIdx.x;            // 1024 = 8 b * (32 qt * 4 s)
    int b = blk & 7;                 // XCD-affine batch
    int rest = blk >> 3;
    int s = rest & 3;
    int qt = rest >> 2;
    int t = threadIdx.x, w = t >> 6, l = t & 63;
    int r = l & 31, h = l >> 5, lx = l & 7;
    int n0w = qt * 128 + w * 32;
    int mbase = s * CHUNK;
    const unsigned short* Q = tq + (size_t)b * NP * FF;
    const unsigned short* K = kp + (size_t)b * NP * FF;
    const unsigned short* V = vz + (size_t)b * FF * NP;

    // Q B-frags: B[col n = r][k f = 16kf + 8h + j]
    f16x8 qf[8];
    #pragma unroll
    for (int kf = 0; kf < 8; ++kf)
        qf[kf] = *reinterpret_cast<const f16x8*>(Q + (size_t)(n0w + r) * FF + kf * 16 + h * 8);

    f32x16 U[4];
    #pragma unroll
    for (int fb = 0; fb < 4; ++fb)
        #pragma unroll
        for (int i = 0; i < 16; ++i) U[fb][i] = 0.f;
    float mrun = -1e30f, lrun = 0.f;

    // staging source bases (pre-swizzled per-lane global addresses)
    const unsigned short* kbase[4];
    const unsigned short* vbase[4];
    #pragma unroll
    for (int i = 0; i < 4; ++i) {
        int seg = w * 4 + i;
        int krow = seg * 4 + (l >> 4);
        kbase[i] = K + (size_t)(mbase + krow) * FF + 8 * ((l & 15) ^ (krow & 7));
        int frow = seg * 8 + (l >> 3);
        vbase[i] = V + (size_t)frow * NP + mbase + 8 * ((l & 7) ^ (frow & 7));
    }

    // prologue: stage tile 0 into buf 0
    #pragma unroll
    for (int i = 0; i < 4; ++i) {
        GLD16(kbase[i], &Kl[0][(w * 4 + i) * 512]);
        GLD16(vbase[i], &Vl[0][(w * 4 + i) * 512]);
    }

    int cur = 0;
    for (int it = 0; it < NIT; ++it) {
        asm volatile("s_waitcnt vmcnt(0)" ::: "memory");
        __builtin_amdgcn_s_barrier();
        asm volatile("" ::: "memory");
        if (it + 1 < NIT) {
            #pragma unroll
            for (int i = 0; i < 4; ++i) {
                GLD16(kbase[i] + (size_t)(it + 1) * 64 * FF, &Kl[cur ^ 1][(w * 4 + i) * 512]);
                GLD16(vbase[i] + (it + 1) * 64, &Vl[cur ^ 1][(w * 4 + i) * 512]);
            }
        }
        const unsigned short* Kb = Kl[cur];
        const unsigned short* Vb = Vl[cur];

        // S^T = K Q^T : 64m x 32n, rows m in regs, col n = r
        f32x16 St0, St1;
        #pragma unroll
        for (int i = 0; i < 16; ++i) { St0[i] = 0.f; St1[i] = 0.f; }
        __builtin_amdgcn_s_setprio(1);
        #pragma unroll
        for (int kf = 0; kf < 8; ++kf) {
            f16x8 a0 = *reinterpret_cast<const f16x8*>(Kb + r * 128 + 8 * ((2 * kf + h) ^ lx));
            f16x8 a1 = *reinterpret_cast<const f16x8*>(Kb + (32 + r) * 128 + 8 * ((2 * kf + h) ^ lx));
            St0 = __builtin_amdgcn_mfma_f32_32x32x16_f16(a0, qf[kf], St0, 0, 0, 0);
            St1 = __builtin_amdgcn_mfma_f32_32x32x16_f16(a1, qf[kf], St1, 0, 0, 0);
        }
        __builtin_amdgcn_s_setprio(0);

        // online softmax: lane owns col n = r, rows m = mt*32 + (reg&3)+8*(reg>>2)+4h
        float pmax = St0[0];
        #pragma unroll
        for (int i = 1; i < 16; ++i) pmax = fmaxf(pmax, St0[i]);
        #pragma unroll
        for (int i = 0; i < 16; ++i) pmax = fmaxf(pmax, St1[i]);
        pmax = fmaxf(pmax, __shfl_xor(pmax, 32));
        if (__any(pmax > mrun + 8.0f)) {        // defer-max, THR=8
            float mnew = fmaxf(mrun, pmax);
            float sc = __expf(mrun - mnew);
            mrun = mnew; lrun *= sc;
            #pragma unroll
            for (int rr = 0; rr < 16; ++rr) {
                float scb = __shfl(sc, (rr & 3) + 8 * (rr >> 2) + 4 * h);
                U[0][rr] *= scb; U[1][rr] *= scb; U[2][rr] *= scb; U[3][rr] *= scb;
            }
        }
        float lsum = 0.f;
        unsigned pka[8], pkb[8];
        #pragma unroll
        for (int rr = 0; rr < 8; ++rr) {
            float e0 = __expf(St0[2 * rr] - mrun);
            float e1 = __expf(St0[2 * rr + 1] - mrun);
            float e2 = __expf(St1[2 * rr] - mrun);
            float e3 = __expf(St1[2 * rr + 1] - mrun);
            lsum += (e0 + e1) + (e2 + e3);
            pka[rr] = __builtin_bit_cast(unsigned, __builtin_amdgcn_cvt_pkrtz(e0, e1));
            pkb[rr] = __builtin_bit_cast(unsigned, __builtin_amdgcn_cvt_pkrtz(e2, e3));
        }
        lsum += __shfl_xor(lsum, 32);
        lrun += lsum;

        // U += P V : rebuild P A-frags in-register (cross-half exchange), V from LDS
        __builtin_amdgcn_s_setprio(1);
        #pragma unroll
        for (int kb = 0; kb < 4; ++kb) {
            int ib = 4 * (kb & 1);
            unsigned p0 = (kb < 2) ? pka[ib + 0] : pkb[ib + 0];
            unsigned p1 = (kb < 2) ? pka[ib + 1] : pkb[ib + 1];
            unsigned p2 = (kb < 2) ? pka[ib + 2] : pkb[ib + 2];
            unsigned p3 = (kb < 2) ? pka[ib + 3] : pkb[ib + 3];
            unsigned x0 = __shfl_xor(p0, 32), x1 = __shfl_xor(p1, 32);
            unsigned y0 = __shfl_xor(p2, 32), y1 = __shfl_xor(p3, 32);
            u32x4 du;
            du[0] = h ? y0 : p0;
            du[1] = h ? y1 : p1;
            du[2] = h ? p2 : x0;
            du[3] = h ? p3 : x1;
            f16x8 af = __builtin_bit_cast(f16x8, du);
            #pragma unroll
            for (int fb = 0; fb < 4; ++fb) {
                f16x8 vf = *reinterpret_cast<const f16x8*>(
                    Vb + (fb * 32 + r) * 64 + 8 * ((2 * kb + h) ^ lx));
                U[fb] = __builtin_amdgcn_mfma_f32_32x32x16_f16(af, vf, U[fb], 0, 0, 0);
            }
        }
        __builtin_amdgcn_s_setprio(0);
        cur ^= 1;
    }

    // partials: Uh[s][b][n][f] = U/l (f16), ml[s][b][n] = (m, l)
    float linv = 1.0f / lrun;
    unsigned short* up = Uh + (size_t)(s * 8 + b) * NP * FF;
    #pragma unroll
    for (int rr = 0; rr < 16; ++rr) {
        int nn = (rr & 3) + 8 * (rr >> 2) + 4 * h;
        float scb = __shfl(linv, nn);
        int n = n0w + nn;
        #pragma unroll
        for (int fb = 0; fb < 4; ++fb)
            up[(size_t)n * FF + fb * 32 + r] = f2h(U[fb][rr] * scb);
    }
    if (l < 32)
        ml[(size_t)(s * 8 + b) * NP + n0w + l] = make_float2(mrun, lrun);
}

// ---------------------------------------------------------------- combine split-KV partials
__global__ __launch_bounds__(256) void combine_kernel(const unsigned short* __restrict__ Uh,
                                                      const float2* __restrict__ ml,
                                                      unsigned short* __restrict__ uT) {
    int row = blockIdx.x * 2 + (threadIdx.x >> 7);   // b*4096 + n
    int f = threadIdx.x & 127;
    float m[SPLIT], lv[SPLIT];
    #pragma unroll
    for (int s = 0; s < SPLIT; ++s) {
        float2 v = ml[(size_t)s * (BB * NP) + row];
        m[s] = v.x; lv[s] = v.y;
    }
    float M = fmaxf(fmaxf(m[0], m[1]), fmaxf(m[2], m[3]));
    float wsum = 0.f, acc = 0.f;
    #pragma unroll
    for (int s = 0; s < SPLIT; ++s) {
        float wgt = __expf(m[s] - M) * lv[s];
        wsum += wgt;
        acc += wgt * h2f(Uh[((size_t)s * (BB * NP) + row) * FF + f]);
    }
    uT[(size_t)row * FF + f] = f2h(acc / wsum);
}

// ---------------------------------------------------------------- final gemm + residual + bn + relu
__global__ __launch_bounds__(256) void final_kernel(const unsigned short* __restrict__ uT,
                                                    const unsigned short* __restrict__ W2,
                                                    const float* __restrict__ b2,
                                                    const float* __restrict__ sres,
                                                    const float* __restrict__ x,
                                                    float* __restrict__ out) {
    __shared__ unsigned short Alds[128 * 72];
    __shared__ unsigned short Blds[128 * 72];
    int blk = blockIdx.x;           // 512 = 8 * 2 * 32
    int b  = blk & 7;
    int r  = blk >> 3;
    int ct = r & 1;
    int nt = r >> 1;
    int c0 = ct << 7, n0 = nt << 7;
    int t = threadIdx.x, w = t >> 6, l = t & 63;
    int wr = (w >> 1) << 6, wc = (w & 1) << 6;

    f32x4 acc[4][4];
    #pragma unroll
    for (int i = 0; i < 4; ++i)
        #pragma unroll
        for (int j = 0; j < 4; ++j)
            acc[i][j] = f32x4{0.f, 0.f, 0.f, 0.f};

    for (int k0 = 0; k0 < 128; k0 += 64) {
        #pragma unroll
        for (int i = 0; i < 4; ++i) {
            int row = i * 32 + (t >> 3);
            int ch = (t & 7) * 8;
            *reinterpret_cast<int4*>(&Alds[row * 72 + ch]) =
                *reinterpret_cast<const int4*>(W2 + (size_t)(c0 + row) * FF + k0 + ch);
            *reinterpret_cast<int4*>(&Blds[row * 72 + ch]) =
                *reinterpret_cast<const int4*>(uT + ((size_t)b * NP + n0 + row) * FF + k0 + ch);
        }
        __syncthreads();
        #pragma unroll
        for (int kk = 0; kk < 2; ++kk) {
            f16x8 af[4], bfr[4];
            #pragma unroll
            for (int mi = 0; mi < 4; ++mi)
                af[mi] = *reinterpret_cast<const f16x8*>(
                    &Alds[(wr + mi * 16 + (l & 15)) * 72 + kk * 32 + (l >> 4) * 8]);
            #pragma unroll
            for (int ni = 0; ni < 4; ++ni)
                bfr[ni] = *reinterpret_cast<const f16x8*>(
                    &Blds[(wc + ni * 16 + (l & 15)) * 72 + kk * 32 + (l >> 4) * 8]);
            #pragma unroll
            for (int mi = 0; mi < 4; ++mi)
                #pragma unroll
                for (int ni = 0; ni < 4; ++ni)
                    acc[mi][ni] = __builtin_amdgcn_mfma_f32_16x16x32_f16(af[mi], bfr[ni], acc[mi][ni], 0, 0, 0);
        }
        __syncthreads();
    }

    const float* xb = x + (size_t)b * CC * NP;
    float* ob = out + (size_t)b * CC * NP;
    #pragma unroll
    for (int mi = 0; mi < 4; ++mi)
        #pragma unroll
        for (int ni = 0; ni < 4; ++ni) {
            int n = n0 + wc + ni * 16 + (l & 15);
            int cb = c0 + wr + mi * 16 + ((l >> 4) << 2);
            #pragma unroll
            for (int rg = 0; rg < 4; ++rg) {
                int c = cb + rg;
                float v = acc[mi][ni][rg] + b2[c] + sres[c] * xb[(size_t)c * NP + n];
                ob[(size_t)c * NP + n] = v > 0.f ? v : 0.f;
            }
        }
}

// ---------------------------------------------------------------- launch
extern "C" void kernel_launch(void* const* d_in, const int* in_sizes, int n_in,
                              void* d_out, int out_size, void* d_ws, size_t ws_size,
                              hipStream_t stream) {
    const float* x = (const float*)d_in[0];
    char* ws = (char*)d_ws;
    // ws layout (bytes)
    unsigned short* W_all = (unsigned short*)(ws);                    // 384*256*2   = 196608
    float*          b_all = (float*)(ws + 196608);                    // 384*4
    unsigned short* W2    = (unsigned short*)(ws + 198144);           // 256*128*2
    float*          b2    = (float*)(ws + 263680);
    float*          sres  = (float*)(ws + 264704);
    unsigned short* xT    = (unsigned short*)(ws + 265728);           // 8*4096*256*2 = 16777216
    unsigned short* tq    = (unsigned short*)(ws + 17042944);         // 8*4096*128*2 = 8388608
    unsigned short* kp    = (unsigned short*)(ws + 25431552);
    unsigned short* vz    = (unsigned short*)(ws + 33820160);
    unsigned short* uT    = (unsigned short*)(ws + 42208768);
    unsigned short* Uh    = (unsigned short*)(ws + 50597376);         // 4*8*4096*128*2 = 33554432
    float2*         ml    = (float2*)(ws + 84151808);                 // 4*8*4096*8 = 1048576
    // end 85200384

    PrepArgs pa;
    pa.w[0]  = (const float*)d_in[1];  pa.bias[0] = (const float*)d_in[2];
    pa.g[0]  = (const float*)d_in[3];  pa.be[0]   = (const float*)d_in[4];
    pa.m[0]  = (const float*)d_in[5];  pa.v[0]    = (const float*)d_in[6];
    pa.w[1]  = (const float*)d_in[7];  pa.bias[1] = (const float*)d_in[8];
    pa.g[1]  = (const float*)d_in[9];  pa.be[1]   = (const float*)d_in[10];
    pa.m[1]  = (const float*)d_in[11]; pa.v[1]    = (const float*)d_in[12];
    pa.w[2]  = (const float*)d_in[13]; pa.bias[2] = (const float*)d_in[14];
    pa.g[2]  = (const float*)d_in[15]; pa.be[2]   = (const float*)d_in[16];
    pa.m[2]  = (const float*)d_in[17]; pa.v[2]    = (const float*)d_in[18];
    pa.pre_w = (const float*)d_in[19]; pa.pre_b   = (const float*)d_in[20];
    pa.post_g = (const float*)d_in[21]; pa.post_be = (const float*)d_in[22];
    pa.post_m = (const float*)d_in[23]; pa.post_v  = (const float*)d_in[24];
    pa.W_all = W_all; pa.b_all = b_all; pa.W2 = W2; pa.b2 = b2; pa.sres = sres;

    prep_kernel<<<dim3(512), dim3(256), 0, stream>>>(pa);
    transpose_x_kernel<<<dim3(2048), dim3(256), 0, stream>>>(x, xT);
    qkv_kernel<<<dim3(768), dim3(256), 0, stream>>>(xT, W_all, b_all, tq, kp, vz);
    attn_kernel<<<dim3(1024), dim3(256), 0, stream>>>(tq, kp, vz, Uh, ml);
    combine_kernel<<<dim3(16384), dim3(256), 0, stream>>>(Uh, ml, uT);
    final_kernel<<<dim3(512), dim3(256), 0, stream>>>(uT, W2, b2, sres, x, (float*)d_out);
}